// Round 10
// baseline (117.795 us; speedup 1.0000x reference)
//
#include <hip/hip_runtime.h>
#include <hip/hip_fp16.h>

#define NCITY 384
#define BATCH 4
#define DIM   128
#define HID   256
#define M_TOT (BATCH * NCITY)   // 1536
#define TR    4                 // rows per block -> 384 blocks (<=512 co-resident)
#define NBLK  (M_TOT / TR)      // 384
#define NTASK (576 + BATCH)     // 576 pair tiles + 4 softmax
#define HALF_FLOATS 8192        // 32 KB half-chunk
#define MAGIC 0x5A5AC3C3D2D24B4BULL

// ---------------------------------------------------------------------------
// sync / wait primitives (raw barrier, counted vmcnt) — R8/R9-proven
// ---------------------------------------------------------------------------
#define VMWAIT8()  do { asm volatile("s_waitcnt vmcnt(8)"  ::: "memory"); \
                        __builtin_amdgcn_sched_barrier(0); } while (0)
#define VMWAIT0()  do { asm volatile("s_waitcnt vmcnt(0)"  ::: "memory"); \
                        __builtin_amdgcn_sched_barrier(0); } while (0)
#define LGKM0()    do { asm volatile("s_waitcnt lgkmcnt(0)" ::: "memory"); \
                        __builtin_amdgcn_sched_barrier(0); } while (0)
#define SBAR()     do { __builtin_amdgcn_s_barrier(); \
                        __builtin_amdgcn_sched_barrier(0); } while (0)

// ---------------------------------------------------------------------------
// packed f16 helpers (raw VOP3P; ROCm header __hmax2 broken on gfx950)
// ---------------------------------------------------------------------------
__device__ __forceinline__ unsigned pk_add(unsigned a, unsigned b) {
    unsigned r; asm("v_pk_add_f16 %0, %1, %2" : "=v"(r) : "v"(a), "v"(b)); return r;
}
__device__ __forceinline__ unsigned pk_max0(unsigned a) {
    unsigned r; asm("v_pk_max_f16 %0, %1, %2" : "=v"(r) : "v"(a), "v"(0u)); return r;
}
__device__ __forceinline__ unsigned pk_fma(unsigned a, unsigned b, unsigned c) {
    unsigned r; asm("v_pk_fma_f16 %0, %1, %2, %3" : "=v"(r) : "v"(a), "v"(b), "v"(c)); return r;
}
__device__ __forceinline__ unsigned pack2(float a, float b) {
    union { __half2 h2; unsigned u; } c;
    c.h2 = __float22half2_rn(make_float2(a, b));
    return c.u;
}
__device__ __forceinline__ float sum2(unsigned u) {
    union { unsigned u; __half2 h2; } c; c.u = u;
    return __low2float(c.h2) + __high2float(c.h2);
}
union H8 { float4 f4; unsigned u[4]; };

// ---------------------------------------------------------------------------
// Stage one 32KB half-chunk global->LDS (8 x global_load_lds dwordx4 / thread).
// ---------------------------------------------------------------------------
__device__ __forceinline__ void stage32(const float* __restrict__ gsrc,
                                        float* lbuf, int tid)
{
    const int lane = tid & 63;
    const int wv   = tid >> 6;
    #pragma unroll
    for (int i = 0; i < 8; ++i) {
        const int slot = i * 4 + wv;              // 0..31, 1KB each
        __builtin_amdgcn_global_load_lds(
            (const __attribute__((address_space(1))) void*)(gsrc + slot * 256 + lane * 4),
            (__attribute__((address_space(3))) void*)(lbuf + slot * 256),
            16, 0, 0);
    }
}

// emb partial over one We2 half [64k x 128d]
__device__ __forceinline__ void emb_half(const float* buf,
                                         const float (*h1_s)[HID],
                                         int tid, int kbase, float4 eacc[TR])
{
    const int d4 = tid & 31;
    const int k0 = (tid >> 5) * 8;
    #pragma unroll
    for (int kb = 0; kb < 8; kb += 4) {
        float4 hv[TR];
        #pragma unroll
        for (int rr = 0; rr < TR; ++rr)
            hv[rr] = *(const float4*)&h1_s[rr][kbase + k0 + kb];
        #pragma unroll
        for (int kk = 0; kk < 4; ++kk) {
            const float4 w4 = *(const float4*)&buf[(k0 + kb + kk) * DIM + d4 * 4];
            #pragma unroll
            for (int rr = 0; rr < TR; ++rr) {
                const float h = ((const float*)&hv[rr])[kk];
                eacc[rr].x = fmaf(h, w4.x, eacc[rr].x);
                eacc[rr].y = fmaf(h, w4.y, eacc[rr].y);
                eacc[rr].z = fmaf(h, w4.z, eacc[rr].z);
                eacc[rr].w = fmaf(h, w4.w, eacc[rr].w);
            }
        }
    }
}

// head-chunk partial over one weight half [32k x 256c]
__device__ __forceinline__ void chunk_half(const float* buf,
                                           const float (*emb_s)[DIM],
                                           int tid, int kbase, float4 cacc[TR])
{
    const int c4 = tid & 63;
    const int k0 = (tid >> 6) * 8;
    #pragma unroll
    for (int kb = 0; kb < 8; kb += 4) {
        float4 ev[TR];
        #pragma unroll
        for (int rr = 0; rr < TR; ++rr)
            ev[rr] = *(const float4*)&emb_s[rr][kbase + k0 + kb];
        #pragma unroll
        for (int kk = 0; kk < 4; ++kk) {
            const float4 w4 = *(const float4*)&buf[(k0 + kb + kk) * HID + c4 * 4];
            #pragma unroll
            for (int rr = 0; rr < TR; ++rr) {
                const float e = ((const float*)&ev[rr])[kk];
                cacc[rr].x = fmaf(e, w4.x, cacc[rr].x);
                cacc[rr].y = fmaf(e, w4.y, cacc[rr].y);
                cacc[rr].z = fmaf(e, w4.z, cacc[rr].z);
                cacc[rr].w = fmaf(e, w4.w, cacc[rr].w);
            }
        }
    }
}

// 4-way cross-wave reduce of head-chunk partials through dead-buffer scratch.
__device__ __forceinline__ void chunk_reduce(float* scr, int tid,
                                             const float4 cacc[TR], float out6[TR])
{
    const int c4 = tid & 63;
    const int wv = tid >> 6;
    SBAR();
    #pragma unroll
    for (int rr = 0; rr < TR; ++rr)
        *(float4*)&scr[(wv * TR + rr) * HID + c4 * 4] = cacc[rr];
    LGKM0(); SBAR();
    #pragma unroll
    for (int rr = 0; rr < TR; ++rr)
        out6[rr] = scr[(0 * TR + rr) * HID + tid] + scr[(1 * TR + rr) * HID + tid]
                 + scr[(2 * TR + rr) * HID + tid] + scr[(3 * TR + rr) * HID + tid];
}

// ---------------------------------------------------------------------------
// SINGLE fused kernel. 384 blocks x 256 threads, ~72 KB LDS -> 2 blocks/CU,
// all 384 co-resident (cap 512) -> flag-waits cannot deadlock.
// Phase 1 (R9 pipeline, TR=4): encoder -> Ai/Aj (f16) + score, publish flag.
// Phase 2: 580 tasks (576 pair tiles + 4 softmax) strided over blocks; each
// task spin-waits only its producer flags (data is replay-invariant, so a
// stale MAGIC flag from a prior replay is benign).
// ---------------------------------------------------------------------------
__global__ __launch_bounds__(256) void fused_kernel(
    const float* __restrict__ cities,
    const float* __restrict__ We1, const float* __restrict__ be1,
    const float* __restrict__ We2, const float* __restrict__ be2,
    const float* __restrict__ Wa1, const float* __restrict__ ba1,
    const float* __restrict__ wa2, const float* __restrict__ ba2,
    const float* __restrict__ Wd1, const float* __restrict__ bd1,
    const float* __restrict__ wd2, const float* __restrict__ bd2,
    float* __restrict__ score, __half* __restrict__ Ai_h, __half* __restrict__ Aj_h,
    unsigned long long* __restrict__ flags,
    float* __restrict__ att, float* __restrict__ p)
{
    __shared__ float wbuf[2 * HALF_FLOATS];  // 64 KB
    __shared__ float h1_s[TR][HID];          // 4 KB
    __shared__ float emb_s[TR][DIM];         // 2 KB
    __shared__ float red2[4][TR];

    float* b0 = wbuf;
    float* b1 = wbuf + HALF_FLOATS;

    const int tid = threadIdx.x;
    const int bid = blockIdx.x;
    const int r0  = bid * TR;

    // ==== PHASE 1: encoder (R9-proven 2-phase pipeline, TR=4) ===============
    const float w0 = We1[tid], w1 = We1[HID + tid], bb1 = be1[tid];
    const float ba1v = ba1[tid], wa2v = wa2[tid], bd1v = bd1[tid];
    const float be2v = be2[tid & (DIM - 1)];
    float cx[TR], cy[TR];
    #pragma unroll
    for (int rr = 0; rr < TR; ++rr) {
        cx[rr] = cities[(r0 + rr) * 2];
        cy[rr] = cities[(r0 + rr) * 2 + 1];
    }
    #pragma unroll
    for (int rr = 0; rr < TR; ++rr)
        h1_s[rr][tid] = fmaxf(fmaf(cx[rr], w0, fmaf(cy[rr], w1, bb1)), 0.f);
    __builtin_amdgcn_sched_barrier(0);

    float4 eacc[TR];
    #pragma unroll
    for (int rr = 0; rr < TR; ++rr) eacc[rr] = make_float4(0.f, 0.f, 0.f, 0.f);

    // We2: h0..h3 -> emb
    stage32(We2,                   b0, tid);
    stage32(We2 + 1 * HALF_FLOATS, b1, tid);
    VMWAIT8(); LGKM0(); SBAR();
    emb_half(b0, h1_s, tid, 0, eacc);
    SBAR();
    stage32(We2 + 2 * HALF_FLOATS, b0, tid);
    VMWAIT8(); SBAR();
    emb_half(b1, h1_s, tid, 64, eacc);
    SBAR();
    stage32(We2 + 3 * HALF_FLOATS, b1, tid);
    VMWAIT8(); SBAR();
    emb_half(b0, h1_s, tid, 128, eacc);
    SBAR();
    stage32(Wa1, b0, tid);                     // h4
    VMWAIT8(); SBAR();
    emb_half(b1, h1_s, tid, 192, eacc);

    // emb reduce (scratch = b1)
    {
        #pragma unroll
        for (int rr = 0; rr < TR; ++rr) {
            eacc[rr].x += __shfl_xor(eacc[rr].x, 32);
            eacc[rr].y += __shfl_xor(eacc[rr].y, 32);
            eacc[rr].z += __shfl_xor(eacc[rr].z, 32);
            eacc[rr].w += __shfl_xor(eacc[rr].w, 32);
        }
        SBAR();
        if ((tid & 63) < 32) {
            const int wv = tid >> 6, d4 = tid & 31;
            #pragma unroll
            for (int rr = 0; rr < TR; ++rr)
                *(float4*)&b1[(wv * TR + rr) * DIM + d4 * 4] = eacc[rr];
        }
        LGKM0(); SBAR();
        #pragma unroll
        for (int j = 0; j < 2; ++j) {
            const int o = tid + j * 256;
            const int rr = o >> 7, d = o & (DIM - 1);
            emb_s[rr][d] = b1[(0 * TR + rr) * DIM + d] + b1[(1 * TR + rr) * DIM + d]
                         + b1[(2 * TR + rr) * DIM + d] + b1[(3 * TR + rr) * DIM + d]
                         + be2v;
        }
        LGKM0(); SBAR();
    }

    float4 cacc[TR];
    float o6[TR];

    // Wa1: h4..h7 -> attention scores
    stage32(Wa1 + 1 * HALF_FLOATS, b1, tid);   // h5
    VMWAIT8(); SBAR();
    #pragma unroll
    for (int rr = 0; rr < TR; ++rr) cacc[rr] = make_float4(0.f, 0.f, 0.f, 0.f);
    chunk_half(b0, emb_s, tid, 0, cacc);
    SBAR();
    stage32(Wa1 + 2 * HALF_FLOATS, b0, tid);   // h6
    VMWAIT8(); SBAR();
    chunk_half(b1, emb_s, tid, 32, cacc);
    SBAR();
    stage32(Wa1 + 3 * HALF_FLOATS, b1, tid);   // h7
    VMWAIT8(); SBAR();
    chunk_half(b0, emb_s, tid, 64, cacc);
    SBAR();
    stage32(Wd1, b0, tid);                     // h8
    VMWAIT8(); SBAR();
    chunk_half(b1, emb_s, tid, 96, cacc);
    chunk_reduce(b1, tid, cacc, o6);
    {
        const int wv = tid >> 6;
        #pragma unroll
        for (int rr = 0; rr < TR; ++rr) {
            float v = fmaxf(o6[rr] + ba1v, 0.f) * wa2v;
            #pragma unroll
            for (int off = 32; off > 0; off >>= 1)
                v += __shfl_down(v, off);
            if ((tid & 63) == 0) red2[wv][rr] = v;
        }
        LGKM0(); SBAR();
        if (tid < TR)
            score[r0 + tid] = red2[0][tid] + red2[1][tid] + red2[2][tid] + red2[3][tid];
        // ba2 dropped: softmax is shift-invariant
    }

    // Wd1 rows 0..127: h8..h11 -> Ai (f16)
    stage32(Wd1 + 1 * HALF_FLOATS, b1, tid);   // h9
    VMWAIT8(); SBAR();
    #pragma unroll
    for (int rr = 0; rr < TR; ++rr) cacc[rr] = make_float4(0.f, 0.f, 0.f, 0.f);
    chunk_half(b0, emb_s, tid, 0, cacc);
    SBAR();
    stage32(Wd1 + 2 * HALF_FLOATS, b0, tid);   // h10
    VMWAIT8(); SBAR();
    chunk_half(b1, emb_s, tid, 32, cacc);
    SBAR();
    stage32(Wd1 + 3 * HALF_FLOATS, b1, tid);   // h11
    VMWAIT8(); SBAR();
    chunk_half(b0, emb_s, tid, 64, cacc);
    SBAR();
    stage32(Wd1 + 4 * HALF_FLOATS, b0, tid);   // h12
    VMWAIT8(); SBAR();
    chunk_half(b1, emb_s, tid, 96, cacc);
    chunk_reduce(b1, tid, cacc, o6);
    #pragma unroll
    for (int rr = 0; rr < TR; ++rr)
        Ai_h[(r0 + rr) * HID + tid] = __float2half(o6[rr] + bd1v);
    SBAR();                                    // b1 free for restage

    // Wd1 rows 128..255: h12..h15 -> Aj (f16)
    stage32(Wd1 + 5 * HALF_FLOATS, b1, tid);   // h13
    VMWAIT8(); SBAR();
    #pragma unroll
    for (int rr = 0; rr < TR; ++rr) cacc[rr] = make_float4(0.f, 0.f, 0.f, 0.f);
    chunk_half(b0, emb_s, tid, 0, cacc);
    SBAR();
    stage32(Wd1 + 6 * HALF_FLOATS, b0, tid);   // h14
    VMWAIT8(); SBAR();
    chunk_half(b1, emb_s, tid, 32, cacc);
    SBAR();
    stage32(Wd1 + 7 * HALF_FLOATS, b1, tid);   // h15
    VMWAIT8(); SBAR();
    chunk_half(b0, emb_s, tid, 64, cacc);
    VMWAIT0(); SBAR();
    chunk_half(b1, emb_s, tid, 96, cacc);
    chunk_reduce(b0, tid, cacc, o6);           // scratch b0 (no more DMA)
    #pragma unroll
    for (int rr = 0; rr < TR; ++rr)
        Aj_h[(r0 + rr) * HID + tid] = __float2half(o6[rr]);
    (void)ba2;

    // publish: all global stores visible, then flag
    __threadfence();
    __syncthreads();
    if (tid == 0)
        __hip_atomic_store(&flags[bid], MAGIC, __ATOMIC_RELAXED,
                           __HIP_MEMORY_SCOPE_AGENT);

    // ==== PHASE 2: pair tiles + softmax ====================================
    const float bd = bd2[0];
    __half*   ai_s = (__half*)wbuf;            // 16 KB overlay
    __half*   aj_s = (__half*)wbuf + 32 * HID; // 16 KB
    unsigned* wd2h = (unsigned*)(wbuf + 8192); // 512 B

    for (int t = bid; t < NTASK; t += NBLK) {
        __syncthreads();                       // LDS reuse guard
        if (t < 576) {
            const int b   = t / 144;
            const int rem = t % 144;
            const int i0  = (rem / 12) * 32;
            const int j0  = (rem % 12) * 32;

            if (tid < 8) {
                const unsigned long long* f = &flags[(b * NCITY + i0) / TR + tid];
                while (__hip_atomic_load(f, __ATOMIC_RELAXED,
                                         __HIP_MEMORY_SCOPE_AGENT) != MAGIC) {}
            } else if (tid < 16) {
                const unsigned long long* f = &flags[(b * NCITY + j0) / TR + (tid - 8)];
                while (__hip_atomic_load(f, __ATOMIC_RELAXED,
                                         __HIP_MEMORY_SCOPE_AGENT) != MAGIC) {}
            }
            __threadfence();
            __syncthreads();

            if (tid < HID / 2) {
                const float2 w2 = *(const float2*)&wd2[tid * 2];
                wd2h[tid] = pack2(w2.x, w2.y);
            }
            for (int u = tid; u < 32 * 32; u += 256) {
                const int r = u >> 5, s = u & 31;
                const int su = (s ^ (r & 15)) * 8;
                *(float4*)&ai_s[r * HID + su] =
                    *(const float4*)&Ai_h[(b * NCITY + i0 + r) * HID + s * 8];
                *(float4*)&aj_s[r * HID + su] =
                    *(const float4*)&Aj_h[(b * NCITY + j0 + r) * HID + s * 8];
            }
            __syncthreads();

            const int tx = tid & 15;
            const int ty = tid >> 4;

            unsigned a00A = 0u, a00B = 0u, a01A = 0u, a01B = 0u;
            unsigned a10A = 0u, a10B = 0u, a11A = 0u, a11B = 0u;

            #pragma unroll 4
            for (int k8 = 0; k8 < 32; ++k8) {
                const int ci = (k8 ^ ty) * 8;
                const int cj = (k8 ^ tx) * 8;
                H8 x0, x1, y0, y1;
                x0.f4 = *(const float4*)&ai_s[ ty       * HID + ci];
                x1.f4 = *(const float4*)&ai_s[(ty + 16) * HID + ci];
                y0.f4 = *(const float4*)&aj_s[ tx       * HID + cj];
                y1.f4 = *(const float4*)&aj_s[(tx + 16) * HID + cj];

                #pragma unroll
                for (int q = 0; q < 4; ++q) {
                    const unsigned w = wd2h[k8 * 4 + q];
                    const unsigned t00 = pk_max0(pk_add(x0.u[q], y0.u[q]));
                    const unsigned t01 = pk_max0(pk_add(x0.u[q], y1.u[q]));
                    const unsigned t10 = pk_max0(pk_add(x1.u[q], y0.u[q]));
                    const unsigned t11 = pk_max0(pk_add(x1.u[q], y1.u[q]));
                    if (q < 2) {
                        a00A = pk_fma(t00, w, a00A);
                        a01A = pk_fma(t01, w, a01A);
                        a10A = pk_fma(t10, w, a10A);
                        a11A = pk_fma(t11, w, a11A);
                    } else {
                        a00B = pk_fma(t00, w, a00B);
                        a01B = pk_fma(t01, w, a01B);
                        a10B = pk_fma(t10, w, a10B);
                        a11B = pk_fma(t11, w, a11B);
                    }
                }
            }

            float accs[2][2];
            accs[0][0] = sum2(a00A) + sum2(a00B);
            accs[0][1] = sum2(a01A) + sum2(a01B);
            accs[1][0] = sum2(a10A) + sum2(a10B);
            accs[1][1] = sum2(a11A) + sum2(a11B);

            #pragma unroll
            for (int ii = 0; ii < 2; ++ii) {
                #pragma unroll
                for (int jj = 0; jj < 2; ++jj) {
                    const int gi = i0 + ty + ii * 16;
                    const int gj = j0 + tx + jj * 16;
                    const float v = 1.f / (1.f + __expf(-(accs[ii][jj] + bd)));
                    p[(b * NCITY + gi) * NCITY + gj] = (gi == gj) ? 0.f : v;
                }
            }
        } else {
            // softmax for batch bb
            const int bb = t - 576;
            if (tid < 96) {
                const unsigned long long* f = &flags[bb * 96 + tid];
                while (__hip_atomic_load(f, __ATOMIC_RELAXED,
                                         __HIP_MEMORY_SCOPE_AGENT) != MAGIC) {}
            }
            __threadfence();
            __syncthreads();

            float* red = wbuf;
            const float v0 = score[bb * NCITY + tid];
            const bool  h2v = (tid < NCITY - 256);
            const float v1 = h2v ? score[bb * NCITY + 256 + tid] : -3.4e38f;
            float m = fmaxf(v0, v1);
            #pragma unroll
            for (int off = 32; off > 0; off >>= 1)
                m = fmaxf(m, __shfl_down(m, off));
            if ((tid & 63) == 0) red[tid >> 6] = m;
            __syncthreads();
            m = fmaxf(fmaxf(red[0], red[1]), fmaxf(red[2], red[3]));
            const float e0 = __expf(v0 - m);
            const float e1 = h2v ? __expf(v1 - m) : 0.f;
            float s = e0 + e1;
            #pragma unroll
            for (int off = 32; off > 0; off >>= 1)
                s += __shfl_down(s, off);
            if ((tid & 63) == 0) red[4 + (tid >> 6)] = s;
            __syncthreads();
            s = red[4] + red[5] + red[6] + red[7];
            att[bb * NCITY + tid] = e0 / s;
            if (h2v) att[bb * NCITY + 256 + tid] = e1 / s;
        }
    }
}

// ---------------------------------------------------------------------------
extern "C" void kernel_launch(void* const* d_in, const int* in_sizes, int n_in,
                              void* d_out, int out_size, void* d_ws, size_t ws_size,
                              hipStream_t stream)
{
    const float* cities = (const float*)d_in[0];
    const float* We1    = (const float*)d_in[1];
    const float* be1    = (const float*)d_in[2];
    const float* We2    = (const float*)d_in[3];
    const float* be2    = (const float*)d_in[4];
    const float* Wa1    = (const float*)d_in[5];
    const float* ba1    = (const float*)d_in[6];
    const float* wa2    = (const float*)d_in[7];
    const float* ba2    = (const float*)d_in[8];
    const float* Wd1    = (const float*)d_in[9];
    const float* bd1    = (const float*)d_in[10];
    const float* wd2    = (const float*)d_in[11];
    const float* bd2    = (const float*)d_in[12];

    float* out_att = (float*)d_out;                 // [4,384]
    float* out_p   = out_att + M_TOT;               // [4,384,384]

    float*  score = (float*)d_ws;                             // 1536 f32
    __half* Ai_h  = (__half*)(score + M_TOT);                 // 1536*256 f16
    __half* Aj_h  = Ai_h + M_TOT * HID;                       // 1536*256 f16
    unsigned long long* flags = (unsigned long long*)(Aj_h + M_TOT * HID); // 384 u64

    fused_kernel<<<NBLK, 256, 0, stream>>>(
        cities, We1, be1, We2, be2, Wa1, ba1, wa2, ba2, Wd1, bd1, wd2, bd2,
        score, Ai_h, Aj_h, flags, out_att, out_p);
}

// Round 11
// 34.010 us; speedup vs baseline: 3.4635x; 3.4635x over previous
//
#include <hip/hip_runtime.h>
#include <hip/hip_fp16.h>

#define NCITY 384
#define BATCH 4
#define DIM   128
#define HID   256
#define M_TOT (BATCH * NCITY)   // 1536
#define TR    6                 // rows per encoder block -> 256 blocks

// ---------------------------------------------------------------------------
// K1: streaming encoder. 256 blocks x 256 threads, ~34 KB LDS -> 4 blocks/CU.
// Weights stream global->registers (coalesced float4, L2-resident, read-once
// per block); LDS only for h1/emb tiles + cross-wave reduce scratch.
// ~8 barriers per block total (reduce points only) — no stage/drain phases.
// Thread mappings and reduction order identical to R2/R9 (absmax 0.0 lineage).
// ---------------------------------------------------------------------------
__device__ __forceinline__ void chunk_stream(
    const float* __restrict__ W,          // [128][256] row-major, global
    const float (*emb_s)[DIM], float* scr, int tid, float out6[TR])
{
    const int c4 = tid & 63;              // 4 output cols: 4*c4
    const int wv = tid >> 6;              // k-split 4: 32 k each
    const int k0 = wv * 32;

    float4 acc[TR];
    #pragma unroll
    for (int rr = 0; rr < TR; ++rr) acc[rr] = make_float4(0.f, 0.f, 0.f, 0.f);

    #pragma unroll 2
    for (int kb = 0; kb < 32; kb += 4) {
        float4 ev[TR];
        #pragma unroll
        for (int rr = 0; rr < TR; ++rr)
            ev[rr] = *(const float4*)&emb_s[rr][k0 + kb];
        #pragma unroll
        for (int kk = 0; kk < 4; ++kk) {
            const float4 w4 = *(const float4*)&W[(k0 + kb + kk) * HID + c4 * 4];
            #pragma unroll
            for (int rr = 0; rr < TR; ++rr) {
                const float e = ((const float*)&ev[rr])[kk];
                acc[rr].x = fmaf(e, w4.x, acc[rr].x);
                acc[rr].y = fmaf(e, w4.y, acc[rr].y);
                acc[rr].z = fmaf(e, w4.z, acc[rr].z);
                acc[rr].w = fmaf(e, w4.w, acc[rr].w);
            }
        }
    }
    __syncthreads();                      // prior scr readers done
    #pragma unroll
    for (int rr = 0; rr < TR; ++rr)
        *(float4*)&scr[(wv * TR + rr) * HID + c4 * 4] = acc[rr];
    __syncthreads();
    #pragma unroll
    for (int rr = 0; rr < TR; ++rr)
        out6[rr] = scr[(0 * TR + rr) * HID + tid] + scr[(1 * TR + rr) * HID + tid]
                 + scr[(2 * TR + rr) * HID + tid] + scr[(3 * TR + rr) * HID + tid];
}

__global__ __launch_bounds__(256, 3) void encoder_stream(
    const float* __restrict__ cities,
    const float* __restrict__ We1, const float* __restrict__ be1,
    const float* __restrict__ We2, const float* __restrict__ be2,
    const float* __restrict__ Wa1, const float* __restrict__ ba1,
    const float* __restrict__ wa2, const float* __restrict__ ba2,
    const float* __restrict__ Wd1, const float* __restrict__ bd1,
    float* __restrict__ score, float* __restrict__ Ai, float* __restrict__ Aj)
{
    __shared__ float h1_s[TR][HID];       // 6 KB
    __shared__ float emb_s[TR][DIM];      // 3 KB
    __shared__ float scr[4 * TR * HID];   // 24 KB reduce scratch
    __shared__ float red2[4][TR];

    const int tid = threadIdx.x;
    const int r0  = blockIdx.x * TR;

    // ---- h1 = relu(cities @ We1 + be1); thread owns k = tid ----------------
    {
        const float w0 = We1[tid], w1 = We1[HID + tid], b1v = be1[tid];
        #pragma unroll
        for (int rr = 0; rr < TR; ++rr) {
            const float cxx = cities[(r0 + rr) * 2];
            const float cyy = cities[(r0 + rr) * 2 + 1];
            h1_s[rr][tid] = fmaxf(fmaf(cxx, w0, fmaf(cyy, w1, b1v)), 0.f);
        }
    }
    __syncthreads();

    // ---- emb = h1 @ We2 + be2 (k-split 8, weights streamed from global) ----
    {
        const int d4 = tid & 31;          // 4 cols: 4*d4
        const int k0 = (tid >> 5) * 32;   // 8 k-groups
        float4 acc[TR];
        #pragma unroll
        for (int rr = 0; rr < TR; ++rr) acc[rr] = make_float4(0.f, 0.f, 0.f, 0.f);

        #pragma unroll 2
        for (int kb = 0; kb < 32; kb += 4) {
            float4 hv[TR];
            #pragma unroll
            for (int rr = 0; rr < TR; ++rr)
                hv[rr] = *(const float4*)&h1_s[rr][k0 + kb];
            #pragma unroll
            for (int kk = 0; kk < 4; ++kk) {
                const float4 w4 = *(const float4*)&We2[(k0 + kb + kk) * DIM + d4 * 4];
                #pragma unroll
                for (int rr = 0; rr < TR; ++rr) {
                    const float h = ((const float*)&hv[rr])[kk];
                    acc[rr].x = fmaf(h, w4.x, acc[rr].x);
                    acc[rr].y = fmaf(h, w4.y, acc[rr].y);
                    acc[rr].z = fmaf(h, w4.z, acc[rr].z);
                    acc[rr].w = fmaf(h, w4.w, acc[rr].w);
                }
            }
        }
        #pragma unroll
        for (int rr = 0; rr < TR; ++rr) {
            acc[rr].x += __shfl_xor(acc[rr].x, 32);
            acc[rr].y += __shfl_xor(acc[rr].y, 32);
            acc[rr].z += __shfl_xor(acc[rr].z, 32);
            acc[rr].w += __shfl_xor(acc[rr].w, 32);
        }
        if ((tid & 63) < 32) {
            const int wv = tid >> 6;
            #pragma unroll
            for (int rr = 0; rr < TR; ++rr)
                *(float4*)&scr[(wv * TR + rr) * DIM + d4 * 4] = acc[rr];
        }
        __syncthreads();
        for (int o = tid; o < TR * DIM; o += 256) {
            const int rr = o >> 7, d = o & (DIM - 1);
            emb_s[rr][d] = scr[(0 * TR + rr) * DIM + d] + scr[(1 * TR + rr) * DIM + d]
                         + scr[(2 * TR + rr) * DIM + d] + scr[(3 * TR + rr) * DIM + d]
                         + be2[d];
        }
        __syncthreads();
    }

    float o6[TR];

    // ---- Wa1 -> attention scores -------------------------------------------
    chunk_stream(Wa1, emb_s, scr, tid, o6);
    {
        const float ba1v = ba1[tid], wa2v = wa2[tid];
        const int wv = tid >> 6;
        #pragma unroll
        for (int rr = 0; rr < TR; ++rr) {
            float v = fmaxf(o6[rr] + ba1v, 0.f) * wa2v;
            #pragma unroll
            for (int off = 32; off > 0; off >>= 1)
                v += __shfl_down(v, off);
            if ((tid & 63) == 0) red2[wv][rr] = v;
        }
        __syncthreads();
        if (tid < TR)
            score[r0 + tid] = red2[0][tid] + red2[1][tid] + red2[2][tid] + red2[3][tid];
        // ba2 dropped: softmax is shift-invariant
    }

    // ---- Wd1 rows 0..127 -> Ai ---------------------------------------------
    chunk_stream(Wd1, emb_s, scr, tid, o6);
    {
        const float bd1v = bd1[tid];
        #pragma unroll
        for (int rr = 0; rr < TR; ++rr)
            Ai[(r0 + rr) * HID + tid] = o6[rr] + bd1v;
    }

    // ---- Wd1 rows 128..255 -> Aj -------------------------------------------
    chunk_stream(Wd1 + DIM * HID, emb_s, scr, tid, o6);
    #pragma unroll
    for (int rr = 0; rr < TR; ++rr)
        Aj[(r0 + rr) * HID + tid] = o6[rr];
    (void)ba2;
}

// ---------------------------------------------------------------------------
// Packed f16 helpers (raw VOP3P; ROCm header __hmax2 broken on gfx950).
// ---------------------------------------------------------------------------
__device__ __forceinline__ unsigned pk_add(unsigned a, unsigned b) {
    unsigned r; asm("v_pk_add_f16 %0, %1, %2" : "=v"(r) : "v"(a), "v"(b)); return r;
}
__device__ __forceinline__ unsigned pk_max0(unsigned a) {
    unsigned r; asm("v_pk_max_f16 %0, %1, %2" : "=v"(r) : "v"(a), "v"(0u)); return r;
}
__device__ __forceinline__ unsigned pk_fma(unsigned a, unsigned b, unsigned c) {
    unsigned r; asm("v_pk_fma_f16 %0, %1, %2, %3" : "=v"(r) : "v"(a), "v"(b), "v"(c)); return r;
}
__device__ __forceinline__ unsigned pack2(float a, float b) {
    union { __half2 h2; unsigned u; } c;
    c.h2 = __float22half2_rn(make_float2(a, b));
    return c.u;
}
__device__ __forceinline__ float sum2(unsigned u) {
    union { unsigned u; __half2 h2; } c; c.u = u;
    return __low2float(c.h2) + __high2float(c.h2);
}
union H8 { float4 f4; unsigned u[4]; };

// ---------------------------------------------------------------------------
// K2: pairwise decoder in packed f16 + fused softmax (verbatim R7 — proven).
// ---------------------------------------------------------------------------
__global__ __launch_bounds__(256) void pair_sm_kernel(
    const float* __restrict__ Ai, const float* __restrict__ Aj,
    const float* __restrict__ wd2, const float* __restrict__ bd2,
    const float* __restrict__ score, float* __restrict__ att,
    float* __restrict__ p)
{
    const int tid = threadIdx.x;
    const int b   = blockIdx.y;

    if (blockIdx.x == 144) {     // ---- softmax block for batch b ------------
        __shared__ float red[8];
        const int t = tid;
        const float v0 = score[b * NCITY + t];
        const bool  h2v = (t < NCITY - 256);
        const float v1 = h2v ? score[b * NCITY + 256 + t] : -3.4e38f;
        float m = fmaxf(v0, v1);
        #pragma unroll
        for (int off = 32; off > 0; off >>= 1)
            m = fmaxf(m, __shfl_down(m, off));
        if ((t & 63) == 0) red[t >> 6] = m;
        __syncthreads();
        m = fmaxf(fmaxf(red[0], red[1]), fmaxf(red[2], red[3]));
        const float e0 = __expf(v0 - m);
        const float e1 = h2v ? __expf(v1 - m) : 0.f;
        float s = e0 + e1;
        #pragma unroll
        for (int off = 32; off > 0; off >>= 1)
            s += __shfl_down(s, off);
        if ((t & 63) == 0) red[4 + (t >> 6)] = s;
        __syncthreads();
        s = red[4] + red[5] + red[6] + red[7];
        att[b * NCITY + t] = e0 / s;
        if (h2v) att[b * NCITY + 256 + t] = e1 / s;
        return;
    }

    // ---- pair tile ---------------------------------------------------------
    __shared__ __half ai_s[32 * HID];    // 16 KB
    __shared__ __half aj_s[32 * HID];    // 16 KB
    __shared__ unsigned wd2h[HID / 2];   // 512 B

    const int i0 = (blockIdx.x / 12) * 32;
    const int j0 = (blockIdx.x % 12) * 32;

    if (tid < HID / 2) {
        const float2 w2 = *(const float2*)&wd2[tid * 2];
        wd2h[tid] = pack2(w2.x, w2.y);
    }

    for (int u = tid; u < 32 * 32; u += 256) {
        const int r = u >> 5, s = u & 31;
        const int su = (s ^ (r & 15)) * 8;
        {
            const int g = (b * NCITY + i0 + r) * HID + s * 8;
            const float4 f0 = *(const float4*)&Ai[g];
            const float4 f1 = *(const float4*)&Ai[g + 4];
            H8 pk;
            pk.u[0] = pack2(f0.x, f0.y);
            pk.u[1] = pack2(f0.z, f0.w);
            pk.u[2] = pack2(f1.x, f1.y);
            pk.u[3] = pack2(f1.z, f1.w);
            *(float4*)&ai_s[r * HID + su] = pk.f4;
        }
        {
            const int g = (b * NCITY + j0 + r) * HID + s * 8;
            const float4 f0 = *(const float4*)&Aj[g];
            const float4 f1 = *(const float4*)&Aj[g + 4];
            H8 pk;
            pk.u[0] = pack2(f0.x, f0.y);
            pk.u[1] = pack2(f0.z, f0.w);
            pk.u[2] = pack2(f1.x, f1.y);
            pk.u[3] = pack2(f1.z, f1.w);
            *(float4*)&aj_s[r * HID + su] = pk.f4;
        }
    }
    __syncthreads();

    const int tx = tid & 15;
    const int ty = tid >> 4;

    unsigned a00A = 0u, a00B = 0u, a01A = 0u, a01B = 0u;
    unsigned a10A = 0u, a10B = 0u, a11A = 0u, a11B = 0u;

    #pragma unroll 4
    for (int k8 = 0; k8 < 32; ++k8) {
        const int ci = (k8 ^ ty) * 8;
        const int cj = (k8 ^ tx) * 8;
        H8 x0, x1, y0, y1;
        x0.f4 = *(const float4*)&ai_s[ ty       * HID + ci];
        x1.f4 = *(const float4*)&ai_s[(ty + 16) * HID + ci];
        y0.f4 = *(const float4*)&aj_s[ tx       * HID + cj];
        y1.f4 = *(const float4*)&aj_s[(tx + 16) * HID + cj];

        #pragma unroll
        for (int q = 0; q < 4; ++q) {
            const unsigned w = wd2h[k8 * 4 + q];
            const unsigned t00 = pk_max0(pk_add(x0.u[q], y0.u[q]));
            const unsigned t01 = pk_max0(pk_add(x0.u[q], y1.u[q]));
            const unsigned t10 = pk_max0(pk_add(x1.u[q], y0.u[q]));
            const unsigned t11 = pk_max0(pk_add(x1.u[q], y1.u[q]));
            if (q < 2) {
                a00A = pk_fma(t00, w, a00A);
                a01A = pk_fma(t01, w, a01A);
                a10A = pk_fma(t10, w, a10A);
                a11A = pk_fma(t11, w, a11A);
            } else {
                a00B = pk_fma(t00, w, a00B);
                a01B = pk_fma(t01, w, a01B);
                a10B = pk_fma(t10, w, a10B);
                a11B = pk_fma(t11, w, a11B);
            }
        }
    }

    const float bd = bd2[0];
    float accs[2][2];
    accs[0][0] = sum2(a00A) + sum2(a00B);
    accs[0][1] = sum2(a01A) + sum2(a01B);
    accs[1][0] = sum2(a10A) + sum2(a10B);
    accs[1][1] = sum2(a11A) + sum2(a11B);

    #pragma unroll
    for (int ii = 0; ii < 2; ++ii) {
        #pragma unroll
        for (int jj = 0; jj < 2; ++jj) {
            const int gi = i0 + ty + ii * 16;
            const int gj = j0 + tx + jj * 16;
            const float v = 1.f / (1.f + __expf(-(accs[ii][jj] + bd)));
            p[(b * NCITY + gi) * NCITY + gj] = (gi == gj) ? 0.f : v;
        }
    }
}

// ---------------------------------------------------------------------------
extern "C" void kernel_launch(void* const* d_in, const int* in_sizes, int n_in,
                              void* d_out, int out_size, void* d_ws, size_t ws_size,
                              hipStream_t stream)
{
    const float* cities = (const float*)d_in[0];
    const float* We1    = (const float*)d_in[1];
    const float* be1    = (const float*)d_in[2];
    const float* We2    = (const float*)d_in[3];
    const float* be2    = (const float*)d_in[4];
    const float* Wa1    = (const float*)d_in[5];
    const float* ba1    = (const float*)d_in[6];
    const float* wa2    = (const float*)d_in[7];
    const float* ba2    = (const float*)d_in[8];
    const float* Wd1    = (const float*)d_in[9];
    const float* bd1    = (const float*)d_in[10];
    const float* wd2    = (const float*)d_in[11];
    const float* bd2    = (const float*)d_in[12];

    float* out_att = (float*)d_out;                 // [4,384]
    float* out_p   = out_att + M_TOT;               // [4,384,384]

    float* score = (float*)d_ws;                    // 1536
    float* Ai    = score + M_TOT;                   // 1536*256
    float* Aj    = Ai + M_TOT * HID;                // 1536*256

    encoder_stream<<<M_TOT / TR, 256, 0, stream>>>(
        cities, We1, be1, We2, be2, Wa1, ba1, wa2, ba2, Wd1, bd1,
        score, Ai, Aj);

    pair_sm_kernel<<<dim3(145, BATCH), 256, 0, stream>>>(
        Ai, Aj, wd2, bd2, score, out_att, out_p);
}